// Round 1
// baseline (1314.479 us; speedup 1.0000x reference)
//
#include <hip/hip_runtime.h>

// NESLinear training path:
//   out[p,o] = sum_d x[p,d] * (W[d,o] + weps[p,d,o]) + bias[o] + beps[p,o]
// P=1024, D=512, O=512, fp32.
// Memory-bound on the 1.07 GB weight_eps stream; target ~172 us @ 6.3 TB/s.

#define NES_P 1024
#define NES_D 512
#define NES_O 512

__global__ __launch_bounds__(128)
void NESLinear_62517543960898_kernel(
    const float* __restrict__ x,     // [P, D]
    const float* __restrict__ w,     // [D, O]
    const float* __restrict__ bias,  // [O]
    const float* __restrict__ weps,  // [P, D, O]
    const float* __restrict__ beps,  // [P, O]
    float* __restrict__ out)         // [P, O]
{
    const int p = blockIdx.x;            // one block per sample p
    const int t = threadIdx.x;           // 0..127, owns o = 4t..4t+3

    // Stage x[p, :] into LDS once (512 floats = 2 KB). Loop reads are
    // wave-uniform -> LDS broadcast, no bank conflicts.
    __shared__ float xs[NES_D];
    #pragma unroll
    for (int i = t; i < NES_D; i += 128) xs[i] = x[p * NES_D + i];
    __syncthreads();

    // float4 base pointers; row stride in float4 units = O/4 = 128
    const float4* eps4 = reinterpret_cast<const float4*>(
                             weps + (size_t)p * NES_D * NES_O) + t;
    const float4* w4   = reinterpret_cast<const float4*>(w) + t;

    float4 acc = make_float4(0.f, 0.f, 0.f, 0.f);

    // d-loop: per iteration each wave streams 1 KiB of weps (coalesced 16B/lane)
    // plus 1 KiB of W (L2-resident). Unrolled for outstanding-load ILP.
    #pragma unroll 2
    for (int d = 0; d < NES_D; d += 4) {
        const float4 xv = *reinterpret_cast<const float4*>(&xs[d]);
        #pragma unroll
        for (int j = 0; j < 4; ++j) {
            const float4 e  = eps4[(size_t)(d + j) * (NES_O / 4)];
            const float4 wv = w4[(d + j) * (NES_O / 4)];
            const float xj = (j == 0) ? xv.x : (j == 1) ? xv.y
                           : (j == 2) ? xv.z : xv.w;
            acc.x = fmaf(xj, wv.x + e.x, acc.x);
            acc.y = fmaf(xj, wv.y + e.y, acc.y);
            acc.z = fmaf(xj, wv.z + e.z, acc.z);
            acc.w = fmaf(xj, wv.w + e.w, acc.w);
        }
    }

    const float4 b  = reinterpret_cast<const float4*>(bias)[t];
    const float4 be = reinterpret_cast<const float4*>(beps + (size_t)p * NES_O)[t];
    acc.x += b.x + be.x;
    acc.y += b.y + be.y;
    acc.z += b.z + be.z;
    acc.w += b.w + be.w;

    reinterpret_cast<float4*>(out + (size_t)p * NES_O)[t] = acc;
}

extern "C" void kernel_launch(void* const* d_in, const int* in_sizes, int n_in,
                              void* d_out, int out_size, void* d_ws, size_t ws_size,
                              hipStream_t stream) {
    const float* x    = (const float*)d_in[0];
    const float* w    = (const float*)d_in[1];
    const float* bias = (const float*)d_in[2];
    const float* weps = (const float*)d_in[3];
    const float* beps = (const float*)d_in[4];
    float* out = (float*)d_out;

    NESLinear_62517543960898_kernel<<<NES_P, 128, 0, stream>>>(
        x, w, bias, weps, beps, out);
}

// Round 2
// 1286.086 us; speedup vs baseline: 1.0221x; 1.0221x over previous
//
#include <hip/hip_runtime.h>

// NESLinear: out[p,o] = sum_d x[p,d]*(W[d,o] + weps[p,d,o]) + bias[o] + beps[p,o]
// P=1024, D=512, O=512 fp32. Memory-bound on the 1.07 GB weps stream.
// Round 2: software-pipelined double-buffered load clauses (4 eps + 4 W
// dwordx4 issued per iteration before consuming previous batch) so each wave
// always has ~4 KB of HBM loads in flight; eps loads nontemporal to keep W
// L2-resident. Target: eps stream at ~6 TB/s -> ~180 us kernel.

#define NES_P 1024
#define NES_D 512
#define NES_O 512
#define OQ    (NES_O / 4)   // 128 float4 per o-row

typedef float f32x4 __attribute__((ext_vector_type(4)));

__global__ __launch_bounds__(128, 2)
void NESLinear_62517543960898_kernel(
    const float* __restrict__ x,     // [P, D]
    const float* __restrict__ w,     // [D, O]
    const float* __restrict__ bias,  // [O]
    const float* __restrict__ weps,  // [P, D, O]
    const float* __restrict__ beps,  // [P, O]
    float* __restrict__ out)         // [P, O]
{
    const int p = blockIdx.x;   // one block per sample p
    const int t = threadIdx.x;  // 0..127, owns o = 4t..4t+3

    // Stage x[p,:] in LDS; loop reads are wave-uniform -> broadcast, no conflicts.
    __shared__ float xs[NES_D];
    #pragma unroll
    for (int i = t; i < NES_D; i += 128) xs[i] = x[p * NES_D + i];
    __syncthreads();

    const f32x4* __restrict__ e4 =
        reinterpret_cast<const f32x4*>(weps + (size_t)p * NES_D * NES_O) + t;
    const f32x4* __restrict__ w4 = reinterpret_cast<const f32x4*>(w) + t;

    // acc starts at bias + bias_eps
    f32x4 acc = reinterpret_cast<const f32x4*>(bias)[t]
              + reinterpret_cast<const f32x4*>(beps + (size_t)p * NES_O)[t];

    // Double-buffered batches of 4 d-rows: 4 eps (HBM, nontemporal) + 4 W (L2).
    f32x4 eb[2][4], wb[2][4];

    #pragma unroll
    for (int j = 0; j < 4; ++j) {
        eb[0][j] = __builtin_nontemporal_load(&e4[j * OQ]);
        wb[0][j] = w4[j * OQ];
    }

    // Main loop: batches kb = 0 .. 126 consumed; batch kb+1 issued first so a
    // full batch is always in flight per wave. unroll 2 makes cur/nxt and the
    // eb/wb indices compile-time constants (registers, no scratch).
    #pragma unroll 2
    for (int kb = 0; kb < NES_D / 4 - 1; ++kb) {
        const int cur = kb & 1;
        const int nxt = cur ^ 1;
        const f32x4* en = e4 + (kb + 1) * 4 * OQ;
        const f32x4* wn = w4 + (kb + 1) * 4 * OQ;
        #pragma unroll
        for (int j = 0; j < 4; ++j) {
            eb[nxt][j] = __builtin_nontemporal_load(&en[j * OQ]);
            wb[nxt][j] = wn[j * OQ];
        }
        #pragma unroll
        for (int j = 0; j < 4; ++j) {
            const float xj = xs[kb * 4 + j];
            acc += xj * (wb[cur][j] + eb[cur][j]);
        }
    }

    { // epilogue: batch 127 (sits in buffer (127 & 1) = 1)
        const int kb = NES_D / 4 - 1;
        const int cur = kb & 1;
        #pragma unroll
        for (int j = 0; j < 4; ++j) {
            const float xj = xs[kb * 4 + j];
            acc += xj * (wb[cur][j] + eb[cur][j]);
        }
    }

    reinterpret_cast<f32x4*>(out + (size_t)p * NES_O)[t] = acc;
}

extern "C" void kernel_launch(void* const* d_in, const int* in_sizes, int n_in,
                              void* d_out, int out_size, void* d_ws, size_t ws_size,
                              hipStream_t stream) {
    const float* x    = (const float*)d_in[0];
    const float* w    = (const float*)d_in[1];
    const float* bias = (const float*)d_in[2];
    const float* weps = (const float*)d_in[3];
    const float* beps = (const float*)d_in[4];
    float* out = (float*)d_out;

    NESLinear_62517543960898_kernel<<<NES_P, 128, 0, stream>>>(
        x, w, bias, weps, beps, out);
}